// Round 13
// baseline (194.606 us; speedup 1.0000x reference)
//
#include <hip/hip_runtime.h>
#include <hip/hip_bf16.h>

typedef __attribute__((ext_vector_type(8))) short short8;
typedef __attribute__((ext_vector_type(4))) short s4v;
typedef __attribute__((ext_vector_type(4))) int   int4v;
typedef __attribute__((ext_vector_type(4))) float floatx4;

#define MFMA16(A,B,C) __builtin_amdgcn_mfma_f32_16x16x32_bf16(A,B,C,0,0,0)

__device__ __forceinline__ short bf16bits(float x) {
    __hip_bfloat16 h = __float2bfloat16(x);
    return *(short*)&h;
}
__device__ __forceinline__ short8 cvt8(const float* p) {
    floatx4 a = *(const floatx4*)p;
    floatx4 b = *(const floatx4*)(p + 4);
    short8 r;
    r[0]=bf16bits(a.x); r[1]=bf16bits(a.y); r[2]=bf16bits(a.z); r[3]=bf16bits(a.w);
    r[4]=bf16bits(b.x); r[5]=bf16bits(b.y); r[6]=bf16bits(b.z); r[7]=bf16bits(b.w);
    return r;
}
// scaled variant for Q: folds 1/sqrt(d) * log2(e) so softmax is a bare v_exp_f32
__device__ __forceinline__ short8 cvt8s(const float* p) {
    constexpr float SCL2 = 0.125f * 1.44269504088896f;
    floatx4 a = *(const floatx4*)p;
    floatx4 b = *(const floatx4*)(p + 4);
    a *= SCL2; b *= SCL2;
    short8 r;
    r[0]=bf16bits(a.x); r[1]=bf16bits(a.y); r[2]=bf16bits(a.z); r[3]=bf16bits(a.w);
    r[4]=bf16bits(b.x); r[5]=bf16bits(b.y); r[6]=bf16bits(b.z); r[7]=bf16bits(b.w);
    return r;
}
// hardware packed f32->bf16 (RNE, identical rounding to __float2bfloat16)
__device__ __forceinline__ int pk2(float lo, float hi) {
    int r;
    asm("v_cvt_pk_bf16_f32 %0, %1, %2" : "=v"(r) : "v"(lo), "v"(hi));
    return r;
}

// ---- prologue (fused): V -> VT [h][d][s] bf16, and K -> K16 bf16 row-major ----
__global__ __launch_bounds__(256) void prep(const float* __restrict__ V,
                                            short* __restrict__ VT,
                                            const float* __restrict__ K,
                                            short* __restrict__ K16, int doK)
{
    __shared__ short tile[64 * 65];
    const int t  = threadIdx.x;
    const int h  = blockIdx.x >> 6;
    const int s0 = (blockIdx.x & 63) << 6;
    const float* src = V + ((size_t)h * 4096 + s0) * 64;
    const int r = t >> 4, dq = (t & 15) * 4;
#pragma unroll
    for (int pass = 0; pass < 4; ++pass) {
        const int s = pass * 16 + r;
        floatx4 f = *(const floatx4*)(src + s * 64 + dq);
        short* w = tile + s * 65 + dq;
        w[0] = bf16bits(f.x); w[1] = bf16bits(f.y);
        w[2] = bf16bits(f.z); w[3] = bf16bits(f.w);
    }
    __syncthreads();
    const int d = t >> 2, sc = (t & 3) * 16;
    short8 a, b;
#pragma unroll
    for (int j = 0; j < 8; ++j) a[j] = tile[(sc + j) * 65 + d];
#pragma unroll
    for (int j = 0; j < 8; ++j) b[j] = tile[(sc + 8 + j) * 65 + d];
    short* dst = VT + ((size_t)h * 64 + d) * 4096 + s0 + sc;
    *(short8*)dst       = a;
    *(short8*)(dst + 8) = b;
    if (doK) {
        const size_t base = (size_t)blockIdx.x * 4096 + (size_t)t * 16;
        *(short8*)(K16 + base)     = cvt8(K + base);
        *(short8*)(K16 + base + 8) = cvt8(K + base + 8);
    }
}

// ---- uniform-makespan pairing: every block runs exactly 32-33 rounds ----
// 1024 blocks = 16 heads x 32 x-values x 2 roles.
//  role 0: tile 63-x, key-tiles [0,33)            -> partial slot even
//  role 1: tile 63-x, key-tiles [33,64-x) (31-x)  -> partial slot odd
//          then tile x, key-tiles [0,x+1)         -> direct output
// Per-round body/staging/mkpf are R10's verified code (bit-identical); the
// ks/ke-bounded loop and the partial+merge machinery are R11's (verified).
// All 4 blocks/CU now finish together -> no drain-phase occupancy decay.
__global__ __attribute__((amdgpu_waves_per_eu(4, 8))) __launch_bounds__(256)
void attn_pair(const float* __restrict__ Qg, const short* __restrict__ K16g,
               const short* __restrict__ VTg, float* __restrict__ Og,
               float* __restrict__ partO, float* __restrict__ partL)
{
    constexpr int S = 4096, D = 64;

    __shared__ __align__(16) short lK[8192];   // 2 x (64 keys x 64 d), swizzled
    __shared__ __align__(16) short lV[8192];   // 2 x (64 d x 64 keys), swizzled

    const int tid = threadIdx.x;
    const int wv  = tid >> 6;
    const int ln  = tid & 63;
    const int ll  = ln & 15;
    const int qd  = ln >> 4;
    const int qhalf = wv & 1;
    const int khalf = wv >> 1;

    const int bid  = blockIdx.x;
    const int h    = bid & 15;
    const int x    = (bid >> 4) & 31;
    const int role = bid >> 9;

    const float* Qh  = Qg  + (size_t)h * S * D;
    const short* K16 = K16g + (size_t)h * S * D;
    const short* Vt  = VTg + (size_t)h * 64 * S;

    // staging addresses (R10-verified)
    const int kkey = tid >> 3, kd8 = tid & 7;
    const int koct = kd8 & 3;
    short* kdst = lK + ((kkey >> 4) * 2 + (kd8 >> 2)) * 512
                     + ((((kkey & 15) | (koct << 4)) ^ (koct * 5)) * 8);
    const short* ksrc6 = K16 + kkey * 64 + kd8 * 8;
    const int vd = tid >> 2, voct = tid & 3;
    short* vdst = lV + (vd >> 4) * 512
                     + ((((vd & 15) | (voct << 4)) ^ (voct * 5)) * 8);
    const short* vsrc = Vt + (size_t)vd * S + voct * 8;
    const int rblk = ((ll | (qd << 4)) ^ (qd * 5));

    short8 ones;
#pragma unroll
    for (int j = 0; j < 8; ++j) ones[j] = (short)0x3F80;  // bf16 1.0

    // one segment = R10's verified main loop over key-tiles [ks,ke) of q-tile
    // qblk; output: slot>=0 -> unnormalized partials, slot<0 -> direct O.
    auto runSeg = [&](int qblk, int ks, int ke, int slot) {
        const int qb     = qblk << 6;
        const int qrow   = qb + (qhalf << 5);
        const int wv_end = qrow + 32;

        short8 qA0, qA1, qB0, qB1;   // pre-scaled Q fragments
        {
            const float* qp = Qh + (qrow + ll) * D + qd * 8;
            qA0 = cvt8s(qp);       qA1 = cvt8s(qp + 32);
            const float* qp2 = qp + 16 * D;
            qB0 = cvt8s(qp2);      qB1 = cvt8s(qp2 + 32);
        }

        floatx4 oA[4], oB[4], olA, olB;
#pragma unroll
        for (int dt = 0; dt < 4; ++dt) { oA[dt] = (floatx4){0.f,0.f,0.f,0.f}; oB[dt] = oA[dt]; }
        olA = (floatx4){0.f,0.f,0.f,0.f};
        olB = olA;

        auto mkpf = [&](floatx4 sc0, floatx4 sc1, int qgrp, int kvh) -> short8 {
            float p0[4], p1[4];
#pragma unroll
            for (int r = 0; r < 4; ++r) { p0[r] = exp2f(sc0[r]); p1[r] = exp2f(sc1[r]); }
            if (kvh + 31 > qgrp) {                 // diagonal tiles only
                const int qg = qgrp + ll;
                const int k0 = kvh + qd * 4, k1 = k0 + 16;
#pragma unroll
                for (int r = 0; r < 4; ++r) {
                    if (k0 + r > qg) p0[r] = 0.f;
                    if (k1 + r > qg) p1[r] = 0.f;
                }
            }
            int w0 = pk2(p0[0], p0[1]);
            int w1 = pk2(p0[2], p0[3]);
            int w2 = pk2(p1[0], p1[1]);
            int w3 = pk2(p1[2], p1[3]);
            asm("v_permlane32_swap_b32 %0, %1" : "+v"(w0), "+v"(w2));
            asm("v_permlane32_swap_b32 %0, %1" : "+v"(w1), "+v"(w3));
            asm("v_permlane16_swap_b32 %0, %1" : "+v"(w0), "+v"(w2));
            asm("v_permlane16_swap_b32 %0, %1" : "+v"(w1), "+v"(w3));
            int4v pv = {w0, w1, w2, w3};
            return *(short8*)&pv;
        };

        short8 kp0 = *(const short8*)(ksrc6 + (size_t)(ks * 64) * 64);
        short8 kp1 = *(const short8*)(ksrc6 + (size_t)(ks * 64 + 32) * 64);
        short8 vp0 = *(const short8*)(vsrc + ks * 64);
        short8 vp1 = *(const short8*)(vsrc + ks * 64 + 32);

        int bo = 0;
        for (int t = ks; t <= ke; ++t) {
            __syncthreads();
            if (t < ke) {
                *(short8*)(kdst + bo)        = kp0;
                *(short8*)(kdst + bo + 2048) = kp1;
                *(short8*)(vdst + bo)        = vp0;
                *(short8*)(vdst + bo + 2048) = vp1;
                if (t + 1 < ke) {
                    const int nk = (t + 1) << 6;
                    kp0 = *(const short8*)(ksrc6 + (size_t)nk * 64);
                    kp1 = *(const short8*)(ksrc6 + (size_t)(nk + 32) * 64);
                    vp0 = *(const short8*)(vsrc + nk);
                    vp1 = *(const short8*)(vsrc + nk + 32);
                }
            }
            if (t > ks) {
                const int kv  = (t - 1) << 6;
                const int kvw = kv + (khalf << 5);
                if (kvw < wv_end) {
                    const int ro = (bo ^ 4096) + (khalf << 11);
                    const short* Kb = lK + ro;
                    const short* Vb = lV + ro;
                    floatx4 zz = (floatx4){0.f,0.f,0.f,0.f};
                    floatx4 sA0=zz, sA1=zz, sB0=zz, sB1=zz;
                    short8 kf;
                    __builtin_amdgcn_s_setprio(1);
                    kf = ((const short8*)(Kb +    0))[rblk]; sA0 = MFMA16(kf, qA0, sA0); sB0 = MFMA16(kf, qB0, sB0);
                    kf = ((const short8*)(Kb +  512))[rblk]; sA0 = MFMA16(kf, qA1, sA0); sB0 = MFMA16(kf, qB1, sB0);
                    kf = ((const short8*)(Kb + 1024))[rblk]; sA1 = MFMA16(kf, qA0, sA1); sB1 = MFMA16(kf, qB0, sB1);
                    kf = ((const short8*)(Kb + 1536))[rblk]; sA1 = MFMA16(kf, qA1, sA1); sB1 = MFMA16(kf, qB1, sB1);
                    __builtin_amdgcn_s_setprio(0);

                    short8 pfA = mkpf(sA0, sA1, qrow,      kvw);
                    short8 pfB = mkpf(sB0, sB1, qrow + 16, kvw);
                    __builtin_amdgcn_s_setprio(1);
#pragma unroll
                    for (int dt = 0; dt < 4; ++dt) {
                        short8 vf = ((const short8*)(Vb + dt * 512))[rblk];
                        oA[dt] = MFMA16(pfA, vf, oA[dt]);
                        oB[dt] = MFMA16(pfB, vf, oB[dt]);
                    }
                    olA = MFMA16(pfA, ones, olA);
                    olB = MFMA16(pfB, ones, olB);
                    __builtin_amdgcn_s_setprio(0);
                }
            }
            bo ^= 4096;
        }

        // khalf merge through LDS scratch (reuses lK/lV)
        __syncthreads();
        float* sAod = (float*)lK;
        float* sBod = (float*)lV;
        const int mbase = ((qhalf << 6) + ln) * 20;
        if (khalf == 1) {
#pragma unroll
            for (int dt = 0; dt < 4; ++dt)
#pragma unroll
                for (int r = 0; r < 4; ++r) {
                    sAod[mbase + dt * 4 + r] = oA[dt][r];
                    sBod[mbase + dt * 4 + r] = oB[dt][r];
                }
#pragma unroll
            for (int r = 0; r < 4; ++r) {
                sAod[mbase + 16 + r] = olA[r];
                sBod[mbase + 16 + r] = olB[r];
            }
        }
        __syncthreads();
        if (khalf == 0) {
#pragma unroll
            for (int dt = 0; dt < 4; ++dt)
#pragma unroll
                for (int r = 0; r < 4; ++r) {
                    oA[dt][r] += sAod[mbase + dt * 4 + r];
                    oB[dt][r] += sBod[mbase + dt * 4 + r];
                }
#pragma unroll
            for (int r = 0; r < 4; ++r) {
                olA[r] += sAod[mbase + 16 + r];
                olB[r] += sBod[mbase + 16 + r];
            }
            if (slot < 0) {
#pragma unroll
                for (int r = 0; r < 4; ++r) {
                    const float rl = 1.f / fmaxf(olA[r], 1e-37f);
                    const int q = qrow + qd * 4 + r;
                    float* op = Og + ((size_t)h * S + q) * D + ll;
#pragma unroll
                    for (int dt = 0; dt < 4; ++dt)
                        op[dt * 16] = oA[dt][r] * rl;
                }
#pragma unroll
                for (int r = 0; r < 4; ++r) {
                    const float rl = 1.f / fmaxf(olB[r], 1e-37f);
                    const int q = qrow + 16 + qd * 4 + r;
                    float* op = Og + ((size_t)h * S + q) * D + ll;
#pragma unroll
                    for (int dt = 0; dt < 4; ++dt)
                        op[dt * 16] = oB[dt][r] * rl;
                }
            } else {
                float* po = partO + (size_t)slot * 4096;
                float* pl = partL + (size_t)slot * 64;
#pragma unroll
                for (int r = 0; r < 4; ++r) {
                    const int row = (qhalf << 5) + qd * 4 + r;
                    float* op = po + row * 64 + ll;
#pragma unroll
                    for (int dt = 0; dt < 4; ++dt)
                        op[dt * 16] = oA[dt][r];
                    if (ll == 0) pl[row] = olA[r];
                }
#pragma unroll
                for (int r = 0; r < 4; ++r) {
                    const int row = (qhalf << 5) + 16 + qd * 4 + r;
                    float* op = po + row * 64 + ll;
#pragma unroll
                    for (int dt = 0; dt < 4; ++dt)
                        op[dt * 16] = oB[dt][r];
                    if (ll == 0) pl[row] = olB[r];
                }
            }
        }
    };

    const int slotBase = (h * 32 + x) * 2;
    if (role == 0) {
        runSeg(63 - x, 0, 33, slotBase);              // 33 rounds
    } else {
        runSeg(63 - x, 33, 64 - x, slotBase + 1);     // 31-x rounds (may be 0)
        runSeg(x, 0, x + 1, -1);                      // x+1 rounds, direct out
    }
}

// ---- merge: combine the two key-range partials of each paired q-tile ----
__global__ __launch_bounds__(256) void merge_pair(const float* __restrict__ pO,
                                                  const float* __restrict__ pL,
                                                  float* __restrict__ Og)
{
    const int bid = blockIdx.x;       // 0..511 = h(low 4 bits pattern below)
    const int h  = bid & 15;
    const int x  = bid >> 4;          // 0..31
    const int qb = (63 - x) << 6;
    const int sb = (h * 32 + x) * 2;
    const size_t b0 = (size_t)sb * 4096;
    const int t = threadIdx.x;
#pragma unroll
    for (int k = 0; k < 4; ++k) {
        const int idx = t * 4 + k * 1024;
        const int row = idx >> 6;
        floatx4 a = *(const floatx4*)(pO + b0 + idx);
        floatx4 b = *(const floatx4*)(pO + b0 + 4096 + idx);
        const float l = pL[sb * 64 + row] + pL[sb * 64 + 64 + row];
        const float rl = 1.f / fmaxf(l, 1e-37f);
        floatx4 o;
        o.x = (a.x + b.x) * rl; o.y = (a.y + b.y) * rl;
        o.z = (a.z + b.z) * rl; o.w = (a.w + b.w) * rl;
        *(floatx4*)(Og + ((size_t)h * 4096 + qb + row) * 64 + (idx & 63)) = o;
    }
}

// ---- R12 kernel (verified champion, 71.9us) as fallback tier ----
template<bool KB16>
__global__ __attribute__((amdgpu_waves_per_eu(4, 8))) __launch_bounds__(256)
void attn_fast(const float* __restrict__ Qg, const float* __restrict__ Kg,
               const short* __restrict__ K16g, const short* __restrict__ VTg,
               float* __restrict__ Og)
{
    constexpr int S = 4096, D = 64;
    __shared__ __align__(16) short lK[8192];
    __shared__ __align__(16) short lV[8192];
    const int tid = threadIdx.x;
    const int wv  = tid >> 6;
    const int ln  = tid & 63;
    const int ll  = ln & 15;
    const int qd  = ln >> 4;
    const int qhalf = wv & 1;
    const int khalf = wv >> 1;
    const int c = blockIdx.x & 255;
    const int s = blockIdx.x >> 8;
    const int h = c & 15;
    const int x = c >> 4;
    const int qblk = (s == 0) ? (63 - x) : (s == 1) ? (32 + x) : (s == 2) ? (31 - x) : x;
    const int qb   = qblk << 6;
    const int qrow = qb + (qhalf << 5);
    const float* Qh  = Qg  + (size_t)h * S * D;
    const float* Kf  = Kg  + (size_t)h * S * D;
    const short* K16 = K16g + (size_t)h * S * D;
    const short* Vt  = VTg + (size_t)h * 64 * S;
    short8 qA0, qA1, qB0, qB1;
    {
        const float* qp = Qh + (qrow + ll) * D + qd * 8;
        qA0 = cvt8s(qp);       qA1 = cvt8s(qp + 32);
        const float* qp2 = qp + 16 * D;
        qB0 = cvt8s(qp2);      qB1 = cvt8s(qp2 + 32);
    }
    floatx4 oA[4], oB[4], olA, olB;
#pragma unroll
    for (int dt = 0; dt < 4; ++dt) { oA[dt] = (floatx4){0.f,0.f,0.f,0.f}; oB[dt] = oA[dt]; }
    olA = (floatx4){0.f,0.f,0.f,0.f};
    olB = olA;
    short8 ones;
#pragma unroll
    for (int j = 0; j < 8; ++j) ones[j] = (short)0x3F80;
    const int kkey = tid >> 3, kd8 = tid & 7;
    const int koct = kd8 & 3;
    short* kdst = lK + ((kkey >> 4) * 2 + (kd8 >> 2)) * 512
                     + ((((kkey & 15) | (koct << 4)) ^ (koct * 5)) * 8);
    const float* ksrcf = Kf  + kkey * 64 + kd8 * 8;
    const short* ksrc6 = K16 + kkey * 64 + kd8 * 8;
    const int vd = tid >> 2, voct = tid & 3;
    short* vdst = lV + (vd >> 4) * 512
                     + ((((vd & 15) | (voct << 4)) ^ (voct * 5)) * 8);
    const short* vsrc = Vt + (size_t)vd * S + voct * 8;
    const int rblk = ((ll | (qd << 4)) ^ (qd * 5));
    const int kv_end = qb + 64;
    const int wv_end = qrow + 32;
    auto ldK = [&](int kv) -> short8 {
        return KB16 ? *(const short8*)(ksrc6 + kv * 64) : cvt8(ksrcf + kv * 64);
    };
    auto mkpf = [&](floatx4 sc0, floatx4 sc1, int qgrp, int kvh) -> short8 {
        float p0[4], p1[4];
#pragma unroll
        for (int r = 0; r < 4; ++r) { p0[r] = exp2f(sc0[r]); p1[r] = exp2f(sc1[r]); }
        if (kvh + 31 > qgrp) {
            const int qg = qgrp + ll;
            const int k0 = kvh + qd * 4, k1 = k0 + 16;
#pragma unroll
            for (int r = 0; r < 4; ++r) {
                if (k0 + r > qg) p0[r] = 0.f;
                if (k1 + r > qg) p1[r] = 0.f;
            }
        }
        int w0 = pk2(p0[0], p0[1]);
        int w1 = pk2(p0[2], p0[3]);
        int w2 = pk2(p1[0], p1[1]);
        int w3 = pk2(p1[2], p1[3]);
        asm("v_permlane32_swap_b32 %0, %1" : "+v"(w0), "+v"(w2));
        asm("v_permlane32_swap_b32 %0, %1" : "+v"(w1), "+v"(w3));
        asm("v_permlane16_swap_b32 %0, %1" : "+v"(w0), "+v"(w2));
        asm("v_permlane16_swap_b32 %0, %1" : "+v"(w1), "+v"(w3));
        int4v pv = {w0, w1, w2, w3};
        return *(short8*)&pv;
    };
    short8 kp0 = ldK(0),  kp1 = ldK(32);
    short8 vp0 = *(const short8*)(vsrc);
    short8 vp1 = *(const short8*)(vsrc + 32);
    const int ntiles = kv_end >> 6;
    int bo = 0;
    for (int t = 0; t <= ntiles; ++t) {
        __syncthreads();
        if (t < ntiles) {
            *(short8*)(kdst + bo)        = kp0;
            *(short8*)(kdst + bo + 2048) = kp1;
            *(short8*)(vdst + bo)        = vp0;
            *(short8*)(vdst + bo + 2048) = vp1;
            const int nk = (t + 1) << 6;
            if (nk < kv_end) {
                kp0 = ldK(nk);
                kp1 = ldK(nk + 32);
                vp0 = *(const short8*)(vsrc + nk);
                vp1 = *(const short8*)(vsrc + nk + 32);
            }
        }
        if (t > 0) {
            const int kv  = (t - 1) << 6;
            const int kvw = kv + (khalf << 5);
            if (kvw < wv_end) {
                const int ro = (bo ^ 4096) + (khalf << 11);
                const short* Kb = lK + ro;
                const short* Vb = lV + ro;
                floatx4 zz = (floatx4){0.f,0.f,0.f,0.f};
                floatx4 sA0=zz, sA1=zz, sB0=zz, sB1=zz;
                short8 kf;
                __builtin_amdgcn_s_setprio(1);
                kf = ((const short8*)(Kb +    0))[rblk]; sA0 = MFMA16(kf, qA0, sA0); sB0 = MFMA16(kf, qB0, sB0);
                kf = ((const short8*)(Kb +  512))[rblk]; sA0 = MFMA16(kf, qA1, sA0); sB0 = MFMA16(kf, qB1, sB0);
                kf = ((const short8*)(Kb + 1024))[rblk]; sA1 = MFMA16(kf, qA0, sA1); sB1 = MFMA16(kf, qB0, sB1);
                kf = ((const short8*)(Kb + 1536))[rblk]; sA1 = MFMA16(kf, qA1, sA1); sB1 = MFMA16(kf, qB1, sB1);
                __builtin_amdgcn_s_setprio(0);
                short8 pfA = mkpf(sA0, sA1, qrow,      kvw);
                short8 pfB = mkpf(sB0, sB1, qrow + 16, kvw);
                __builtin_amdgcn_s_setprio(1);
#pragma unroll
                for (int dt = 0; dt < 4; ++dt) {
                    short8 vf = ((const short8*)(Vb + dt * 512))[rblk];
                    oA[dt] = MFMA16(pfA, vf, oA[dt]);
                    oB[dt] = MFMA16(pfB, vf, oB[dt]);
                }
                olA = MFMA16(pfA, ones, olA);
                olB = MFMA16(pfB, ones, olB);
                __builtin_amdgcn_s_setprio(0);
            }
        }
        bo ^= 4096;
    }
    __syncthreads();
    float* sAod = (float*)lK;
    float* sBod = (float*)lV;
    const int mbase = ((qhalf << 6) + ln) * 20;
    if (khalf == 1) {
#pragma unroll
        for (int dt = 0; dt < 4; ++dt)
#pragma unroll
            for (int r = 0; r < 4; ++r) {
                sAod[mbase + dt * 4 + r] = oA[dt][r];
                sBod[mbase + dt * 4 + r] = oB[dt][r];
            }
#pragma unroll
        for (int r = 0; r < 4; ++r) {
            sAod[mbase + 16 + r] = olA[r];
            sBod[mbase + 16 + r] = olB[r];
        }
    }
    __syncthreads();
    if (khalf == 0) {
#pragma unroll
        for (int dt = 0; dt < 4; ++dt)
#pragma unroll
            for (int r = 0; r < 4; ++r) {
                oA[dt][r] += sAod[mbase + dt * 4 + r];
                oB[dt][r] += sBod[mbase + dt * 4 + r];
            }
#pragma unroll
        for (int r = 0; r < 4; ++r) {
            olA[r] += sAod[mbase + 16 + r];
            olB[r] += sBod[mbase + 16 + r];
        }
#pragma unroll
        for (int r = 0; r < 4; ++r) {
            const float rl = 1.f / fmaxf(olA[r], 1e-37f);
            const int q = qrow + qd * 4 + r;
            float* op = Og + ((size_t)h * S + q) * D + ll;
#pragma unroll
            for (int dt = 0; dt < 4; ++dt)
                op[dt * 16] = oA[dt][r] * rl;
        }
#pragma unroll
        for (int r = 0; r < 4; ++r) {
            const float rl = 1.f / fmaxf(olB[r], 1e-37f);
            const int q = qrow + 16 + qd * 4 + r;
            float* op = Og + ((size_t)h * S + q) * D + ll;
#pragma unroll
            for (int dt = 0; dt < 4; ++dt)
                op[dt * 16] = oB[dt][r] * rl;
        }
    }
}

// ---- fallback (round-3 verified kernel, no workspace needed) ----
__global__ __launch_bounds__(256, 4)
void attn_legacy(const float* __restrict__ Qg, const float* __restrict__ Kg,
                 const float* __restrict__ Vg, float* __restrict__ Og)
{
    constexpr int S = 4096, D = 64;
    constexpr float SCL2 = 0.125f * 1.44269504088896f;
    constexpr float NEG  = -1.0e30f;
    __shared__ __align__(16) short lK[2048];
    __shared__ __align__(16) short lV[2048];
    __shared__ __align__(16) short lP[2048];
    const int tid = threadIdx.x, wv = tid >> 6, ln = tid & 63, ll = ln & 15, qd = ln >> 4;
    const int bid = blockIdx.x, h = bid & 15, qblk = 63 - (bid >> 4), qb = qblk << 6;
    const float* Qh = Qg + (size_t)h * S * D;
    const float* Kh = Kg + (size_t)h * S * D;
    const float* Vh = Vg + (size_t)h * S * D;
    const int qrow = qb + wv * 16;
    short8 qf0, qf1;
    { const float* qp = Qh + (qrow + ll) * D + qd * 8; qf0 = cvt8(qp); qf1 = cvt8(qp + 32); }
    floatx4 o[4]; float mi[4], li[4];
#pragma unroll
    for (int dt = 0; dt < 4; ++dt) o[dt] = (floatx4){0.f,0.f,0.f,0.f};
#pragma unroll
    for (int r = 0; r < 4; ++r) { mi[r] = NEG; li[r] = 0.f; }
    const int k_st = tid >> 3, dbase = (tid & 7) * 8;
    const int sq = (dbase >> 3) & 3, sks = dbase >> 5;
    const int kw_slot = (((k_st >> 4) * 2 + sks) * 64)
                      + (((sq << 4) | (k_st & 15)) ^ (sq | (sks << 2)));
    const int kr0 = ln ^ qd, kr1 = ln ^ (qd | 4), vbit3 = (ln >> 3) & 1;
    const int kv_end = qb + 64, wv_end = qrow + 16;
    for (int kv = 0; kv < kv_end; kv += 32) {
        __syncthreads();
        {
            short8 kval = cvt8(Kh + (kv + k_st) * D + dbase);
            ((short8*)lK)[kw_slot] = kval;
            short8 vval = cvt8(Vh + (kv + k_st) * D + dbase);
            const int vq = (k_st >> 3) << 4, vj = k_st & 7;
#pragma unroll
            for (int i = 0; i < 8; ++i) {
                int d = dbase + i, dt = d >> 4, l2 = d & 15;
                int lp = (vq | l2) ^ (((l2 >> 3) & 1) | (dt << 1));
                lV[dt * 512 + lp * 8 + vj] = vval[i];
            }
        }
        __syncthreads();
        if (kv < wv_end) {
            floatx4 sc0 = (floatx4){0.f,0.f,0.f,0.f}, sc1 = sc0; short8 kf;
            kf = ((const short8*)lK)[0*64+kr0]; sc0 = MFMA16(qf0, kf, sc0);
            kf = ((const short8*)lK)[1*64+kr1]; sc0 = MFMA16(qf1, kf, sc0);
            kf = ((const short8*)lK)[2*64+kr0]; sc1 = MFMA16(qf0, kf, sc1);
            kf = ((const short8*)lK)[3*64+kr1]; sc1 = MFMA16(qf1, kf, sc1);
            float p0[4], p1[4]; const int qg = qrow + qd * 4;
#pragma unroll
            for (int r = 0; r < 4; ++r) { p0[r] = sc0[r]*SCL2; p1[r] = sc1[r]*SCL2; }
            if (kv + 31 > qrow) {
                const int k0 = kv + ll, k1 = kv + 16 + ll;
#pragma unroll
                for (int r = 0; r < 4; ++r) {
                    if (k0 > qg + r) p0[r] = NEG;
                    if (k1 > qg + r) p1[r] = NEG;
                }
            }
#pragma unroll
            for (int r = 0; r < 4; ++r) {
                float mx = fmaxf(p0[r], p1[r]);
                mx = fmaxf(mx, __shfl_xor(mx,1)); mx = fmaxf(mx, __shfl_xor(mx,2));
                mx = fmaxf(mx, __shfl_xor(mx,4)); mx = fmaxf(mx, __shfl_xor(mx,8));
                const float nm = fmaxf(mi[r], mx);
                const float a = exp2f(mi[r] - nm); mi[r] = nm;
                p0[r] = exp2f(p0[r] - nm); p1[r] = exp2f(p1[r] - nm);
                float ps = p0[r] + p1[r];
                ps += __shfl_xor(ps,1); ps += __shfl_xor(ps,2);
                ps += __shfl_xor(ps,4); ps += __shfl_xor(ps,8);
                li[r] = li[r] * a + ps;
#pragma unroll
                for (int dt = 0; dt < 4; ++dt) o[dt][r] *= a;
            }
            {
                const int pbase = wv * 512 + (ll & 7);
                const int dl0 = ((ll >> 3) << 4) + qd * 4;
#pragma unroll
                for (int r = 0; r < 4; ++r) {
                    lP[pbase + (dl0 + r) * 8]      = bf16bits(p0[r]);
                    lP[pbase + (dl0 + 32 + r) * 8] = bf16bits(p1[r]);
                }
            }
            __threadfence_block();
            short8 pf = ((const short8*)lP)[wv * 64 + ln];
#pragma unroll
            for (int dt = 0; dt < 4; ++dt) {
                short8 vf = ((const short8*)lV)[dt * 64 + (ln ^ (vbit3 | (dt << 1)))];
                o[dt] = MFMA16(pf, vf, o[dt]);
            }
        }
    }
#pragma unroll
    for (int r = 0; r < 4; ++r) {
        const float rl = 1.f / fmaxf(li[r], 1e-30f);
        const int q = qrow + qd * 4 + r;
        float* op = Og + ((size_t)h * S + q) * D + ll;
#pragma unroll
        for (int dt = 0; dt < 4; ++dt) op[dt * 16] = o[dt][r] * rl;
    }
}

extern "C" void kernel_launch(void* const* d_in, const int* in_sizes, int n_in,
                              void* d_out, int out_size, void* d_ws, size_t ws_size,
                              hipStream_t stream) {
    const float* Q = (const float*)d_in[0];
    const float* K = (const float*)d_in[1];
    const float* V = (const float*)d_in[2];
    float* O = (float*)d_out;
    const size_t elems  = (size_t)16 * 4096 * 64;
    const size_t oneBuf = elems * sizeof(short);               // 8.39 MB
    const size_t partOB = (size_t)1024 * 4096 * sizeof(float); // 16.78 MB
    const size_t partLB = (size_t)1024 * 64 * sizeof(float);   // 256 KB
    if (ws_size >= 2 * oneBuf + partOB + partLB) {
        short* VT  = (short*)d_ws;
        short* K16 = (short*)d_ws + elems;
        float* pO  = (float*)((char*)d_ws + 2 * oneBuf);
        float* pL  = pO + (size_t)1024 * 4096;
        prep<<<dim3(1024), dim3(256), 0, stream>>>(V, VT, K, K16, 1);
        attn_pair<<<dim3(1024), dim3(256), 0, stream>>>(Q, K16, VT, O, pO, pL);
        merge_pair<<<dim3(512), dim3(256), 0, stream>>>(pO, pL, O);
    } else if (ws_size >= 2 * oneBuf) {
        short* VT  = (short*)d_ws;
        short* K16 = (short*)d_ws + elems;
        prep<<<dim3(1024), dim3(256), 0, stream>>>(V, VT, K, K16, 1);
        attn_fast<true><<<dim3(1024), dim3(256), 0, stream>>>(Q, K, K16, VT, O);
    } else if (ws_size >= oneBuf) {
        short* VT = (short*)d_ws;
        prep<<<dim3(1024), dim3(256), 0, stream>>>(V, VT, K, VT, 0);
        attn_fast<false><<<dim3(1024), dim3(256), 0, stream>>>(Q, K, nullptr, VT, O);
    } else {
        attn_legacy<<<dim3(1024), dim3(256), 0, stream>>>(Q, K, V, O);
    }
}

// Round 14
// 184.899 us; speedup vs baseline: 1.0525x; 1.0525x over previous
//
#include <hip/hip_runtime.h>
#include <hip/hip_bf16.h>

typedef __attribute__((ext_vector_type(8))) short short8;
typedef __attribute__((ext_vector_type(4))) short s4v;
typedef __attribute__((ext_vector_type(4))) int   int4v;
typedef __attribute__((ext_vector_type(4))) float floatx4;

#define MFMA16(A,B,C) __builtin_amdgcn_mfma_f32_16x16x32_bf16(A,B,C,0,0,0)

__device__ __forceinline__ short bf16bits(float x) {
    __hip_bfloat16 h = __float2bfloat16(x);
    return *(short*)&h;
}
__device__ __forceinline__ short8 cvt8(const float* p) {
    floatx4 a = *(const floatx4*)p;
    floatx4 b = *(const floatx4*)(p + 4);
    short8 r;
    r[0]=bf16bits(a.x); r[1]=bf16bits(a.y); r[2]=bf16bits(a.z); r[3]=bf16bits(a.w);
    r[4]=bf16bits(b.x); r[5]=bf16bits(b.y); r[6]=bf16bits(b.z); r[7]=bf16bits(b.w);
    return r;
}
// scaled variant for Q: folds 1/sqrt(d) * log2(e) so softmax is a bare v_exp_f32
__device__ __forceinline__ short8 cvt8s(const float* p) {
    constexpr float SCL2 = 0.125f * 1.44269504088896f;
    floatx4 a = *(const floatx4*)p;
    floatx4 b = *(const floatx4*)(p + 4);
    a *= SCL2; b *= SCL2;
    short8 r;
    r[0]=bf16bits(a.x); r[1]=bf16bits(a.y); r[2]=bf16bits(a.z); r[3]=bf16bits(a.w);
    r[4]=bf16bits(b.x); r[5]=bf16bits(b.y); r[6]=bf16bits(b.z); r[7]=bf16bits(b.w);
    return r;
}
// hardware packed f32->bf16 (RNE, identical rounding to __float2bfloat16)
__device__ __forceinline__ int pk2(float lo, float hi) {
    int r;
    asm("v_cvt_pk_bf16_f32 %0, %1, %2" : "=v"(r) : "v"(lo), "v"(hi));
    return r;
}

// ---- prologue (fused): V -> VT [h][d][s] bf16, and K -> K16 bf16 row-major ----
__global__ __launch_bounds__(256) void prep(const float* __restrict__ V,
                                            short* __restrict__ VT,
                                            const float* __restrict__ K,
                                            short* __restrict__ K16, int doK)
{
    __shared__ short tile[64 * 65];
    const int t  = threadIdx.x;
    const int h  = blockIdx.x >> 6;
    const int s0 = (blockIdx.x & 63) << 6;
    const float* src = V + ((size_t)h * 4096 + s0) * 64;
    const int r = t >> 4, dq = (t & 15) * 4;
#pragma unroll
    for (int pass = 0; pass < 4; ++pass) {
        const int s = pass * 16 + r;
        floatx4 f = *(const floatx4*)(src + s * 64 + dq);
        short* w = tile + s * 65 + dq;
        w[0] = bf16bits(f.x); w[1] = bf16bits(f.y);
        w[2] = bf16bits(f.z); w[3] = bf16bits(f.w);
    }
    __syncthreads();
    const int d = t >> 2, sc = (t & 3) * 16;
    short8 a, b;
#pragma unroll
    for (int j = 0; j < 8; ++j) a[j] = tile[(sc + j) * 65 + d];
#pragma unroll
    for (int j = 0; j < 8; ++j) b[j] = tile[(sc + 8 + j) * 65 + d];
    short* dst = VT + ((size_t)h * 64 + d) * 4096 + s0 + sc;
    *(short8*)dst       = a;
    *(short8*)(dst + 8) = b;
    if (doK) {
        const size_t base = (size_t)blockIdx.x * 4096 + (size_t)t * 16;
        *(short8*)(K16 + base)     = cvt8(K + base);
        *(short8*)(K16 + base + 8) = cvt8(K + base + 8);
    }
}

// ---- main: R12 champion (71.9us) + 2x-unrolled loop with CONSTANT buffer
// offsets. R13 refuted the drain-occupancy theory (uniform makespan -> same
// 31%); VALU (54%) is the largest pipe. The runtime bo toggle forced per-round
// address recompute on all 12 LDS ops; unrolling even/odd iterations makes the
// buffer offset a compile-time 0/4096 so LDS addresses are loop-invariant regs
// + ds offset immediates. Barrier/hazard structure identical to R10/R12
// (verified: 1 barrier per tile, stage/compute on opposite buffers).
template<bool KB16>
__global__ __attribute__((amdgpu_waves_per_eu(4, 8))) __launch_bounds__(256)
void attn_fast(const float* __restrict__ Qg, const float* __restrict__ Kg,
               const short* __restrict__ K16g, const short* __restrict__ VTg,
               float* __restrict__ Og)
{
    constexpr int S = 4096, D = 64;

    __shared__ __align__(16) short lK[8192];   // 2 x (64 keys x 64 d), swizzled
    __shared__ __align__(16) short lV[8192];   // 2 x (64 d x 64 keys), swizzled

    const int tid = threadIdx.x;
    const int wv  = tid >> 6;        // 0..3
    const int ln  = tid & 63;
    const int ll  = ln & 15;
    const int qd  = ln >> 4;
    const int qhalf = wv & 1;        // which 32 q-rows of the 64-q block tile
    const int khalf = wv >> 1;       // which 32-key half of each 64-key tile

    // balanced qblk mapping: per-CU sets {63-x, 32+x, 31-x, x}
    const int c = blockIdx.x & 255;
    const int s = blockIdx.x >> 8;
    const int h = c & 15;
    const int x = c >> 4;
    const int qblk = (s == 0) ? (63 - x) : (s == 1) ? (32 + x) : (s == 2) ? (31 - x) : x;
    const int qb   = qblk << 6;
    const int qrow = qb + (qhalf << 5);       // wave owns 32 q-rows

    const float* Qh  = Qg  + (size_t)h * S * D;
    const float* Kf  = Kg  + (size_t)h * S * D;
    const short* K16 = K16g + (size_t)h * S * D;
    const short* Vt  = VTg + (size_t)h * 64 * S;

    // Q fragments for both 16-row groups, pre-scaled
    short8 qA0, qA1, qB0, qB1;
    {
        const float* qp = Qh + (qrow + ll) * D + qd * 8;
        qA0 = cvt8s(qp);       qA1 = cvt8s(qp + 32);
        const float* qp2 = qp + 16 * D;
        qB0 = cvt8s(qp2);      qB1 = cvt8s(qp2 + 32);
    }

    floatx4 oA[4], oB[4], olA, olB;
#pragma unroll
    for (int dt = 0; dt < 4; ++dt) { oA[dt] = (floatx4){0.f,0.f,0.f,0.f}; oB[dt] = oA[dt]; }
    olA = (floatx4){0.f,0.f,0.f,0.f};
    olB = olA;

    short8 ones;
#pragma unroll
    for (int j = 0; j < 8; ++j) ones[j] = (short)0x3F80;  // bf16 1.0

    // K staging (R1/R4 pattern): thread t -> key=t>>3 (0..31) per 32-key subtile
    const int kkey = tid >> 3, kd8 = tid & 7;
    const int koct = kd8 & 3;
    short* kdst = lK + ((kkey >> 4) * 2 + (kd8 >> 2)) * 512
                     + ((((kkey & 15) | (koct << 4)) ^ (koct * 5)) * 8);
    const float* ksrcf = Kf  + kkey * 64 + kd8 * 8;
    const short* ksrc6 = K16 + kkey * 64 + kd8 * 8;
    // V staging: thread t -> d=t>>2 (0..63), key-octet=t&3 (from VT)
    const int vd = tid >> 2, voct = tid & 3;
    short* vdst = lV + (vd >> 4) * 512
                     + ((((vd & 15) | (voct << 4)) ^ (voct * 5)) * 8);
    const short* vsrc = Vt + (size_t)vd * S + voct * 8;
    // fragment read block (lK / lV)
    const int rblk = ((ll | (qd << 4)) ^ (qd * 5));
    const int roK  = khalf << 11;    // loop-invariant fragment base offset

    const int kv_end = qb + 64;          // keys needed by the 64-q block tile
    const int wv_end = qrow + 32;        // this wave's causal limit

    auto ldK = [&](int kv) -> short8 {
        return KB16 ? *(const short8*)(ksrc6 + kv * 64) : cvt8(ksrcf + kv * 64);
    };

    // softmax + in-register P->A-fragment transpose (HW-verified R4):
    // P32(w0,w2), P32(w1,w3), P16(w0,w2), P16(w1,w3)
    auto mkpf = [&](floatx4 sc0, floatx4 sc1, int qgrp, int kvh) -> short8 {
        float p0[4], p1[4];
#pragma unroll
        for (int r = 0; r < 4; ++r) { p0[r] = exp2f(sc0[r]); p1[r] = exp2f(sc1[r]); }
        if (kvh + 31 > qgrp) {                 // diagonal tiles only
            const int qg = qgrp + ll;
            const int k0 = kvh + qd * 4, k1 = k0 + 16;
#pragma unroll
            for (int r = 0; r < 4; ++r) {
                if (k0 + r > qg) p0[r] = 0.f;
                if (k1 + r > qg) p1[r] = 0.f;
            }
        }
        int w0 = pk2(p0[0], p0[1]);
        int w1 = pk2(p0[2], p0[3]);
        int w2 = pk2(p1[0], p1[1]);
        int w3 = pk2(p1[2], p1[3]);
        asm("v_permlane32_swap_b32 %0, %1" : "+v"(w0), "+v"(w2));
        asm("v_permlane32_swap_b32 %0, %1" : "+v"(w1), "+v"(w3));
        asm("v_permlane16_swap_b32 %0, %1" : "+v"(w0), "+v"(w2));
        asm("v_permlane16_swap_b32 %0, %1" : "+v"(w1), "+v"(w3));
        int4v pv = {w0, w1, w2, w3};
        return *(short8*)&pv;
    };

    short8 kp0 = ldK(0),  kp1 = ldK(32);
    short8 vp0 = *(const short8*)(vsrc);
    short8 vp1 = *(const short8*)(vsrc + 32);

    // stage tile t into buffer at constant offset BUF, then prefetch t+1
    auto stageT = [&](int t, int BUF) {
        *(short8*)(kdst + BUF)        = kp0;
        *(short8*)(kdst + BUF + 2048) = kp1;
        *(short8*)(vdst + BUF)        = vp0;
        *(short8*)(vdst + BUF + 2048) = vp1;
        const int nk = (t + 1) << 6;
        if (nk < kv_end) {
            kp0 = ldK(nk);
            kp1 = ldK(nk + 32);
            vp0 = *(const short8*)(vsrc + nk);
            vp1 = *(const short8*)(vsrc + nk + 32);
        }
    };
    // compute tile at key offset kv from buffer at constant offset BUF
    auto computeT = [&](int kv, int BUF) {
        const int kvw = kv + (khalf << 5);    // this wave's 32-key half
        if (kvw < wv_end) {
            const short* Kb = lK + BUF + roK;
            const short* Vb = lV + BUF + roK;
            // S^T = K Q^T; each kf feeds both q-groups (2x reuse)
            floatx4 zz = (floatx4){0.f,0.f,0.f,0.f};
            floatx4 sA0=zz, sA1=zz, sB0=zz, sB1=zz;
            short8 kf;
            __builtin_amdgcn_s_setprio(1);
            kf = ((const short8*)(Kb +    0))[rblk]; sA0 = MFMA16(kf, qA0, sA0); sB0 = MFMA16(kf, qB0, sB0);
            kf = ((const short8*)(Kb +  512))[rblk]; sA0 = MFMA16(kf, qA1, sA0); sB0 = MFMA16(kf, qB1, sB0);
            kf = ((const short8*)(Kb + 1024))[rblk]; sA1 = MFMA16(kf, qA0, sA1); sB1 = MFMA16(kf, qB0, sB1);
            kf = ((const short8*)(Kb + 1536))[rblk]; sA1 = MFMA16(kf, qA1, sA1); sB1 = MFMA16(kf, qB1, sB1);
            __builtin_amdgcn_s_setprio(0);

            // softmax -> in-reg P fragments (32 keys each) -> PV
            short8 pfA = mkpf(sA0, sA1, qrow,      kvw);
            short8 pfB = mkpf(sB0, sB1, qrow + 16, kvw);
            __builtin_amdgcn_s_setprio(1);
#pragma unroll
            for (int dt = 0; dt < 4; ++dt) {
                short8 vf = ((const short8*)(Vb + dt * 512))[rblk];
                oA[dt] = MFMA16(pfA, vf, oA[dt]);
                oB[dt] = MFMA16(pfB, vf, oB[dt]);
            }
            olA = MFMA16(pfA, ones, olA);
            olB = MFMA16(pfB, ones, olB);
            __builtin_amdgcn_s_setprio(0);
        }
    };

    const int ntiles = kv_end >> 6;
    // 2x-unrolled pipeline; per original: iter t = {barrier; stage(t, buf[t&1]);
    // compute(t-1, buf[(t-1)&1])}. Even half: BUF=0 stage / 4096 compute;
    // odd half: BUF=4096 stage / 0 compute. Guards preserve exact semantics
    // for any ntiles >= 1.
    for (int t = 0; t <= ntiles; t += 2) {
        __syncthreads();
        if (t < ntiles) stageT(t, 0);
        if (t > 0)      computeT((t - 1) << 6, 4096);
        __syncthreads();
        if (t + 1 < ntiles) stageT(t + 1, 4096);
        if (t < ntiles)     computeT(t << 6, 0);
    }

    // ---- split-K merge: plain-exp softmax => pure addition of O and row-sums.
    // khalf=1 waves publish partials via lK/lV scratch; khalf=0 combine + store.
    __syncthreads();
    float* sAod = (float*)lK;            // 2 x 64 lanes x 20 floats = 10 KB
    float* sBod = (float*)lV;
    const int mbase = ((qhalf << 6) + ln) * 20;
    if (khalf == 1) {
#pragma unroll
        for (int dt = 0; dt < 4; ++dt)
#pragma unroll
            for (int r = 0; r < 4; ++r) {
                sAod[mbase + dt * 4 + r] = oA[dt][r];
                sBod[mbase + dt * 4 + r] = oB[dt][r];
            }
#pragma unroll
        for (int r = 0; r < 4; ++r) {
            sAod[mbase + 16 + r] = olA[r];
            sBod[mbase + 16 + r] = olB[r];
        }
    }
    __syncthreads();
    if (khalf == 0) {
#pragma unroll
        for (int dt = 0; dt < 4; ++dt)
#pragma unroll
            for (int r = 0; r < 4; ++r) {
                oA[dt][r] += sAod[mbase + dt * 4 + r];
                oB[dt][r] += sBod[mbase + dt * 4 + r];
            }
#pragma unroll
        for (int r = 0; r < 4; ++r) {
            olA[r] += sAod[mbase + 16 + r];
            olB[r] += sBod[mbase + 16 + r];
        }
#pragma unroll
        for (int r = 0; r < 4; ++r) {
            const float rl = 1.f / fmaxf(olA[r], 1e-37f);
            const int q = qrow + qd * 4 + r;
            float* op = Og + ((size_t)h * S + q) * D + ll;
#pragma unroll
            for (int dt = 0; dt < 4; ++dt)
                op[dt * 16] = oA[dt][r] * rl;
        }
#pragma unroll
        for (int r = 0; r < 4; ++r) {
            const float rl = 1.f / fmaxf(olB[r], 1e-37f);
            const int q = qrow + 16 + qd * 4 + r;
            float* op = Og + ((size_t)h * S + q) * D + ll;
#pragma unroll
            for (int dt = 0; dt < 4; ++dt)
                op[dt * 16] = oB[dt][r] * rl;
        }
    }
}

// ---- fallback (round-3 verified kernel, no workspace needed) ----
__global__ __launch_bounds__(256, 4)
void attn_legacy(const float* __restrict__ Qg, const float* __restrict__ Kg,
                 const float* __restrict__ Vg, float* __restrict__ Og)
{
    constexpr int S = 4096, D = 64;
    constexpr float SCL2 = 0.125f * 1.44269504088896f;
    constexpr float NEG  = -1.0e30f;
    __shared__ __align__(16) short lK[2048];
    __shared__ __align__(16) short lV[2048];
    __shared__ __align__(16) short lP[2048];
    const int tid = threadIdx.x, wv = tid >> 6, ln = tid & 63, ll = ln & 15, qd = ln >> 4;
    const int bid = blockIdx.x, h = bid & 15, qblk = 63 - (bid >> 4), qb = qblk << 6;
    const float* Qh = Qg + (size_t)h * S * D;
    const float* Kh = Kg + (size_t)h * S * D;
    const float* Vh = Vg + (size_t)h * S * D;
    const int qrow = qb + wv * 16;
    short8 qf0, qf1;
    { const float* qp = Qh + (qrow + ll) * D + qd * 8; qf0 = cvt8(qp); qf1 = cvt8(qp + 32); }
    floatx4 o[4]; float mi[4], li[4];
#pragma unroll
    for (int dt = 0; dt < 4; ++dt) o[dt] = (floatx4){0.f,0.f,0.f,0.f};
#pragma unroll
    for (int r = 0; r < 4; ++r) { mi[r] = NEG; li[r] = 0.f; }
    const int k_st = tid >> 3, dbase = (tid & 7) * 8;
    const int sq = (dbase >> 3) & 3, sks = dbase >> 5;
    const int kw_slot = (((k_st >> 4) * 2 + sks) * 64)
                      + (((sq << 4) | (k_st & 15)) ^ (sq | (sks << 2)));
    const int kr0 = ln ^ qd, kr1 = ln ^ (qd | 4), vbit3 = (ln >> 3) & 1;
    const int kv_end = qb + 64, wv_end = qrow + 16;
    for (int kv = 0; kv < kv_end; kv += 32) {
        __syncthreads();
        {
            short8 kval = cvt8(Kh + (kv + k_st) * D + dbase);
            ((short8*)lK)[kw_slot] = kval;
            short8 vval = cvt8(Vh + (kv + k_st) * D + dbase);
            const int vq = (k_st >> 3) << 4, vj = k_st & 7;
#pragma unroll
            for (int i = 0; i < 8; ++i) {
                int d = dbase + i, dt = d >> 4, l2 = d & 15;
                int lp = (vq | l2) ^ (((l2 >> 3) & 1) | (dt << 1));
                lV[dt * 512 + lp * 8 + vj] = vval[i];
            }
        }
        __syncthreads();
        if (kv < wv_end) {
            floatx4 sc0 = (floatx4){0.f,0.f,0.f,0.f}, sc1 = sc0; short8 kf;
            kf = ((const short8*)lK)[0*64+kr0]; sc0 = MFMA16(qf0, kf, sc0);
            kf = ((const short8*)lK)[1*64+kr1]; sc0 = MFMA16(qf1, kf, sc0);
            kf = ((const short8*)lK)[2*64+kr0]; sc1 = MFMA16(qf0, kf, sc1);
            kf = ((const short8*)lK)[3*64+kr1]; sc1 = MFMA16(qf1, kf, sc1);
            float p0[4], p1[4]; const int qg = qrow + qd * 4;
#pragma unroll
            for (int r = 0; r < 4; ++r) { p0[r] = sc0[r]*SCL2; p1[r] = sc1[r]*SCL2; }
            if (kv + 31 > qrow) {
                const int k0 = kv + ll, k1 = kv + 16 + ll;
#pragma unroll
                for (int r = 0; r < 4; ++r) {
                    if (k0 > qg + r) p0[r] = NEG;
                    if (k1 > qg + r) p1[r] = NEG;
                }
            }
#pragma unroll
            for (int r = 0; r < 4; ++r) {
                float mx = fmaxf(p0[r], p1[r]);
                mx = fmaxf(mx, __shfl_xor(mx,1)); mx = fmaxf(mx, __shfl_xor(mx,2));
                mx = fmaxf(mx, __shfl_xor(mx,4)); mx = fmaxf(mx, __shfl_xor(mx,8));
                const float nm = fmaxf(mi[r], mx);
                const float a = exp2f(mi[r] - nm); mi[r] = nm;
                p0[r] = exp2f(p0[r] - nm); p1[r] = exp2f(p1[r] - nm);
                float ps = p0[r] + p1[r];
                ps += __shfl_xor(ps,1); ps += __shfl_xor(ps,2);
                ps += __shfl_xor(ps,4); ps += __shfl_xor(ps,8);
                li[r] = li[r] * a + ps;
#pragma unroll
                for (int dt = 0; dt < 4; ++dt) o[dt][r] *= a;
            }
            {
                const int pbase = wv * 512 + (ll & 7);
                const int dl0 = ((ll >> 3) << 4) + qd * 4;
#pragma unroll
                for (int r = 0; r < 4; ++r) {
                    lP[pbase + (dl0 + r) * 8]      = bf16bits(p0[r]);
                    lP[pbase + (dl0 + 32 + r) * 8] = bf16bits(p1[r]);
                }
            }
            __threadfence_block();
            short8 pf = ((const short8*)lP)[wv * 64 + ln];
#pragma unroll
            for (int dt = 0; dt < 4; ++dt) {
                short8 vf = ((const short8*)lV)[dt * 64 + (ln ^ (vbit3 | (dt << 1)))];
                o[dt] = MFMA16(pf, vf, o[dt]);
            }
        }
    }
#pragma unroll
    for (int r = 0; r < 4; ++r) {
        const float rl = 1.f / fmaxf(li[r], 1e-30f);
        const int q = qrow + qd * 4 + r;
        float* op = Og + ((size_t)h * S + q) * D + ll;
#pragma unroll
        for (int dt = 0; dt < 4; ++dt) op[dt * 16] = o[dt][r] * rl;
    }
}

extern "C" void kernel_launch(void* const* d_in, const int* in_sizes, int n_in,
                              void* d_out, int out_size, void* d_ws, size_t ws_size,
                              hipStream_t stream) {
    const float* Q = (const float*)d_in[0];
    const float* K = (const float*)d_in[1];
    const float* V = (const float*)d_in[2];
    float* O = (float*)d_out;
    const size_t elems  = (size_t)16 * 4096 * 64;
    const size_t oneBuf = elems * sizeof(short);          // 8.39 MB
    if (ws_size >= 2 * oneBuf) {
        short* VT  = (short*)d_ws;
        short* K16 = (short*)d_ws + elems;
        prep<<<dim3(1024), dim3(256), 0, stream>>>(V, VT, K, K16, 1);
        attn_fast<true><<<dim3(1024), dim3(256), 0, stream>>>(Q, K, K16, VT, O);
    } else if (ws_size >= oneBuf) {
        short* VT = (short*)d_ws;
        prep<<<dim3(1024), dim3(256), 0, stream>>>(V, VT, K, VT, 0);
        attn_fast<false><<<dim3(1024), dim3(256), 0, stream>>>(Q, K, nullptr, VT, O);
    } else {
        attn_legacy<<<dim3(1024), dim3(256), 0, stream>>>(Q, K, V, O);
    }
}